// Round 11
// baseline (560.802 us; speedup 1.0000x reference)
//
#include <hip/hip_runtime.h>
#include <hip/hip_bf16.h>

#define NN 100000   // nodes
#define NE 500000   // edges
#define FD 128      // input features
#define HD 64       // hidden
#define RR 16       // relations
#define NBASE 30    // bases
#define GG 1000     // graphs
#define CC 10       // classes
#define NGROUP 6250 // NN/16
#define NBLK ((NE + 255) / 256)   // 1954 edge-blocks
#define NDBLK ((NN + 256) / 256)  // 391 dst-scan blocks (covers NN+1 cells)
#define NOBLK (NN / 16)           // 6250 k_out blocks
#define NPBLK ((NGROUP + 3) / 4)  // 1563 proj blocks (64 rows each)
#define TOTZ (NN * RR)            // ints zeroed in k_prep tail: hist2 only
#define ZBLK ((TOTZ + 1023) / 1024)

// Per-node 64-vectors (hroot_bf, xw_bf, h_bf) are stored sigma-order:
// stored[(c&15)*4 + (c>>4)] = true[c] (MFMA C-layout interleave). Wt/w2t have
// contraction dim sigma-permuted to match.
// wcat2 is stored in MFMA B-fragment order: [(nt*4+s)][lane l=q*16+m][8 bf16].
// y_bf is ELIMINATED (was a 128 MB HBM round-trip): k_out gathers h[src] per
// (dst, relation) into LDS s[16][16][64] f32 (LDS atomicAdd, inv-weighted),
// then computes sum_r s_r @ W_r via an MFMA accumulation chain + h@w2 + b2,
// then the proven block-partial pooled epilogue (psum_p/pmax_p [NOBLK][2][64]).
// esen packs type into src's high bits: se.x = src | (type<<20); gconv masks.
// LDS dim index is XOR-swizzled (dim ^ ((dd&7)<<3), same on write+read) to
// break the 16-way bank conflict of 64-f32-stride rows without padding.
// bounds (graph row ends) computed in k_prep.

typedef __attribute__((ext_vector_type(8))) short bf16x8;
typedef __attribute__((ext_vector_type(4))) float f32x4;

__device__ inline unsigned short f2b(float x) {
  __hip_bfloat16 b = __float2bfloat16(x);
  return *reinterpret_cast<unsigned short*>(&b);
}
__device__ inline float b2f(unsigned short u) {
  return __uint_as_float(((unsigned)u) << 16);
}
__device__ inline unsigned pk2(float a, float b) {
  return (unsigned)f2b(a) | ((unsigned)f2b(b) << 16);
}

__device__ inline int block_scan_incl(int v, int* ps, int t) {
  ps[t] = v;
  __syncthreads();
  for (int off = 1; off < 256; off <<= 1) {
    int u = (t >= off) ? ps[t - off] : 0;
    __syncthreads();
    ps[t] += u;
    __syncthreads();
  }
  return ps[t];
}

// ---------------- fused prep: Wt + wcat2 + w2t + bounds + zero(hist2) ----------------
__global__ void k_prep(const float* comp, const float* bases, const float* w_root,
                       const float* w_rel, const float* w2, const int* seq,
                       unsigned short* Wt, unsigned short* wcat2, unsigned short* w2t,
                       int* zbase, int* bounds) {
  int bx = blockIdx.x;
  if (bx < 256) {
    int idx = bx * 256 + threadIdx.x;  // r*4096 + k*64 + n
    int r = idx >> 12, kj = idx & 4095;
    int k = kj >> 6, n = kj & 63;
    float acc = 0.0f;
    for (int b = 0; b < NBASE; ++b)
      acc += comp[r * NBASE + b] * bases[b * 4096 + kj];
    int sk = (k & 15) * 4 + (k >> 4);
    Wt[(r << 12) + n * 64 + sk] = f2b(acc);
  } else if (bx < 336) {
    int idx = (bx - 256) * 256 + threadIdx.x;
    if (idx < 16384) {
      int n = idx >> 7, k = idx & 127;   // n: output col 0..127, k: input 0..127
      float v = (n < 64) ? w_root[k * 64 + n] : w_rel[k * 64 + (n - 64)];
      int nt = n >> 4, m = n & 15;
      int s = k >> 5, q = (k >> 3) & 3, j = k & 7;
      wcat2[(((nt * 4 + s) * 64) + q * 16 + m) * 8 + j] = f2b(v);
    } else if (idx < 16384 + 4096) {
      int i2 = idx - 16384;
      int n = i2 >> 6, k = i2 & 63;
      int sk = (k & 15) * 4 + (k >> 4);
      w2t[n * 64 + sk] = f2b(w2[k * 64 + n]);
    }
  } else if (bx == 336) {
    // bounds = inclusive cumsum of seq (1000), 250 threads x 4
    __shared__ int ps[256];
    int t = threadIdx.x;
    int loc[4];
    int ss = 0;
    if (t < 250) {
      for (int i = 0; i < 4; ++i) { loc[i] = seq[t * 4 + i]; ss += loc[i]; }
    }
    int incl = block_scan_incl(ss, ps, t);
    int base = incl - ss;
    if (t < 250) {
      int run = base;
      for (int i = 0; i < 4; ++i) { run += loc[i]; bounds[t * 4 + i] = run; }
    }
  } else {
    // zero hist2 (NN*RR ints), 1024 ints per block via int4
    int idx = (bx - 337) * 1024 + threadIdx.x * 4;
    if (idx < TOTZ)
      *reinterpret_cast<int4*>(zbase + idx) = make_int4(0, 0, 0, 0);
  }
}

// ---------------- fused: hists (blocks 0..NBLK-1) + proj MFMA (blocks NBLK..) ----------
__global__ __launch_bounds__(256) void k_projhists(
    const float* x, const unsigned short* wcat2, const float* b1,
    unsigned short* hroot_bf, unsigned short* xw_bf,
    const int* ei, const int* etype, int* hist2) {
  __shared__ unsigned short wsh[16384];  // 32 KB, fragment-ordered (proj branch)
  if (blockIdx.x < NBLK) {
    // ---- hists: per-(dst,type) histogram ----
    int e = blockIdx.x * 256 + threadIdx.x;
    if (e < NE)
      atomicAdd(&hist2[ei[NE + e] * RR + etype[e]], 1);
    return;
  }
  // ---- proj: hroot_bf / xw_bf (sigma), LDS-staged weights ----
  int bx = blockIdx.x - NBLK;
  int wv = threadIdx.x >> 6, l = threadIdx.x & 63, m = l & 15, q = l >> 4;
  int g = bx * 4 + wv;
  bool active = (g < NGROUP);
  int gc = active ? g : (NGROUP - 1);   // clamp so OOB waves still reach barrier
  size_t n0 = (size_t)gc * 16;
  const float* xr = x + (n0 + m) * FD + q * 8;
  float4 xv[8];
#pragma unroll
  for (int s = 0; s < 4; ++s) {
    xv[2 * s] = *reinterpret_cast<const float4*>(xr + s * 32);
    xv[2 * s + 1] = *reinterpret_cast<const float4*>(xr + s * 32 + 4);
  }
  // stage weights -> LDS (32 KB), 256 threads x 16B x 8 rounds
  {
    const uint4* wsrc = reinterpret_cast<const uint4*>(wcat2);
    uint4* wdst = reinterpret_cast<uint4*>(wsh);
#pragma unroll
    for (int r = 0; r < 8; ++r)
      wdst[r * 256 + threadIdx.x] = wsrc[r * 256 + threadIdx.x];
  }
  __syncthreads();
  if (!active) return;   // no barriers after this point
  bf16x8 afr[4];
#pragma unroll
  for (int s = 0; s < 4; ++s) {
    float4 xa = xv[2 * s], xb = xv[2 * s + 1];
    bf16x8 a;
    a[0] = (short)f2b(xa.x); a[1] = (short)f2b(xa.y);
    a[2] = (short)f2b(xa.z); a[3] = (short)f2b(xa.w);
    a[4] = (short)f2b(xb.x); a[5] = (short)f2b(xb.y);
    a[6] = (short)f2b(xb.z); a[7] = (short)f2b(xb.w);
    afr[s] = a;
  }
  f32x4 acc[8];
#pragma unroll
  for (int nt = 0; nt < 8; ++nt) acc[nt] = (f32x4){0, 0, 0, 0};
#pragma unroll
  for (int s = 0; s < 4; ++s) {
#pragma unroll
    for (int nt = 0; nt < 8; ++nt) {
      bf16x8 b = *reinterpret_cast<const bf16x8*>(wsh + (size_t)((nt * 4 + s) * 64 + l) * 8);
      acc[nt] = __builtin_amdgcn_mfma_f32_16x16x32_bf16(afr[s], b, acc[nt], 0, 0, 0);
    }
  }
  float bv[4];
#pragma unroll
  for (int nt = 0; nt < 4; ++nt) bv[nt] = b1[nt * 16 + m];
#pragma unroll
  for (int i = 0; i < 4; ++i) {
    size_t row = (n0 + q * 4 + i) * 64 + m * 4;  // sigma: stored = m*4 + nt
    uint2 oh, ox;
    oh.x = pk2(acc[0][i] + bv[0], acc[1][i] + bv[1]);
    oh.y = pk2(acc[2][i] + bv[2], acc[3][i] + bv[3]);
    ox.x = pk2(acc[4][i], acc[5][i]);
    ox.y = pk2(acc[6][i], acc[7][i]);
    *reinterpret_cast<uint2*>(hroot_bf + row) = oh;
    *reinterpret_cast<uint2*>(xw_bf + row) = ox;
  }
}

// ---------------- per-dst scan (391 blocks over NN+1 cells) ----------------
__device__ inline int dst_degree(const int* hist2, int dst) {
  const int4* hp = reinterpret_cast<const int4*>(hist2 + dst * RR);
  int4 a = hp[0], b = hp[1], c = hp[2], d = hp[3];
  return a.x + a.y + a.z + a.w + b.x + b.y + b.z + b.w +
         c.x + c.y + c.z + c.w + d.x + d.y + d.z + d.w;
}

__global__ void k_scanA(const int* hist2, int* bsum) {
  __shared__ int red[256];
  int t = threadIdx.x;
  int dst = blockIdx.x * 256 + t;
  red[t] = (dst < NN) ? dst_degree(hist2, dst) : 0;
  __syncthreads();
  for (int s = 128; s; s >>= 1) {
    if (t < s) red[t] += red[t + s];
    __syncthreads();
  }
  if (t == 0) bsum[blockIdx.x] = red[0];
}

// exclusive scan of bsum[0..NDBLK), single block
__global__ void k_bsum(int* bsum) {
  __shared__ int ps[256];
  int t = threadIdx.x;
  int i0 = t * 2, i1 = t * 2 + 1;
  int l0 = (i0 < NDBLK) ? bsum[i0] : 0;
  int l1 = (i1 < NDBLK) ? bsum[i1] : 0;
  int sa = l0 + l1;
  int incla = block_scan_incl(sa, ps, t);
  int run = incla - sa;
  if (i0 < NDBLK) bsum[i0] = run;
  run += l0;
  if (i1 < NDBLK) bsum[i1] = run;
}

__global__ void k_scanC(const int* hist2, const int* bsum, int* rowptr_d, int* ctr_d) {
  int t = threadIdx.x;
  int dst = blockIdx.x * 256 + t;
  int v = (dst < NN) ? dst_degree(hist2, dst) : 0;
  __shared__ int ps[256];
  int incl = block_scan_incl(v, ps, t);
  int ex = bsum[blockIdx.x] + incl - v;
  if (dst <= NN) { rowptr_d[dst] = ex; ctr_d[dst] = ex; }
}

// ---------------- sort: per-dst pos slots; type packed into esen.x high bits ----------------
__global__ void k_sort(const int* ei, const int* etype, const float* enorm,
                       int* ctr_d, uint2* esen) {
  int e = blockIdx.x * 256 + threadIdx.x;
  if (e >= NE) return;
  int t = etype[e];
  int src = ei[e];
  int dst = ei[NE + e];
  int pos = atomicAdd(&ctr_d[dst], 1);        // random, low-contention
  esen[pos] = make_uint2((unsigned)src | ((unsigned)t << 20), __float_as_uint(enorm[e]));
}

// ---------------- GraphConv segment-sum: 4 edges/iter, uint2 loads (sigma space) ----------------
__global__ __launch_bounds__(256) void k_gconv_seg(const int* rowptr_d, const uint2* esen,
    const unsigned short* xw_bf, const unsigned short* hroot_bf, unsigned short* h_bf) {
  int wv = threadIdx.x >> 6, l = threadIdx.x & 63;
  int c4 = l & 15, eq = l >> 4;
  int dst = blockIdx.x * 4 + wv;
  int lo = rowptr_d[dst];
  int hi = rowptr_d[dst + 1];
  float4 acc = {0.0f, 0.0f, 0.0f, 0.0f};
  for (int base0 = lo; base0 < hi; base0 += 64) {
    int n = min(64, hi - base0);
    int sv = 0;
    float nv = 0.0f;
    if (l < n) {
      uint2 se = esen[base0 + l];
      sv = (int)(se.x & 0xFFFFFu);
      nv = __uint_as_float(se.y);
    }
    int k4max = (n + 3) >> 2;
    for (int k4 = 0; k4 < k4max; ++k4) {
      int eid = k4 * 4 + eq;
      int s = __shfl(sv, eid);
      float w = __shfl(nv, eid);
      if (eid < n) {
        uint2 v = *reinterpret_cast<const uint2*>(xw_bf + (size_t)s * 64 + c4 * 4);
        acc.x += b2f((unsigned short)(v.x & 0xffffu)) * w;
        acc.y += b2f((unsigned short)(v.x >> 16)) * w;
        acc.z += b2f((unsigned short)(v.y & 0xffffu)) * w;
        acc.w += b2f((unsigned short)(v.y >> 16)) * w;
      }
    }
  }
  acc.x += __shfl_xor(acc.x, 16); acc.y += __shfl_xor(acc.y, 16);
  acc.z += __shfl_xor(acc.z, 16); acc.w += __shfl_xor(acc.w, 16);
  acc.x += __shfl_xor(acc.x, 32); acc.y += __shfl_xor(acc.y, 32);
  acc.z += __shfl_xor(acc.z, 32); acc.w += __shfl_xor(acc.w, 32);
  if (l < 16) {
    uint2 hb = *reinterpret_cast<const uint2*>(hroot_bf + (size_t)dst * 64 + l * 4);
    acc.x += b2f((unsigned short)(hb.x & 0xffffu));
    acc.y += b2f((unsigned short)(hb.x >> 16));
    acc.z += b2f((unsigned short)(hb.y & 0xffffu));
    acc.w += b2f((unsigned short)(hb.y >> 16));
    uint2 o;
    o.x = pk2(acc.x, acc.y);
    o.y = pk2(acc.z, acc.w);
    *reinterpret_cast<uint2*>(h_bf + (size_t)dst * 64 + l * 4) = o;
  }
}

// ---------------- fused RGCN+out: per-(dst,r) LDS aggregate -> MFMA chain -> pooled ----------------
__global__ __launch_bounds__(256) void k_out(const int* rowptr_d, const uint2* esen,
    const int* hist2, const unsigned short* h_bf, const unsigned short* Wt,
    const unsigned short* w2t, const float* b2, const int* bounds,
    float* psum_p, float* pmax_p) {
  __shared__ float s_lds[16 * 16 * 64];   // 64 KB: [dd][r][dim ^ ((dd&7)<<3)]
  int wv = threadIdx.x >> 6, l = threadIdx.x & 63;
  int c4 = l & 15, eq = l >> 4;
  size_t d0 = (size_t)blockIdx.x * 16;
  // zero s_lds (16384 f32 / 256 threads = 16 float4 each)
  {
    float4* sz = reinterpret_cast<float4*>(s_lds);
#pragma unroll
    for (int i = 0; i < 16; ++i)
      sz[i * 256 + threadIdx.x] = make_float4(0.0f, 0.0f, 0.0f, 0.0f);
  }
  __syncthreads();
  // phase 1: accumulate inv-weighted h[src] rows into s_lds[dd][type][*]
  for (int dd4 = 0; dd4 < 4; ++dd4) {
    int dd = wv * 4 + dd4;
    int dst = (int)d0 + dd;
    int lo = rowptr_d[dst], hi = rowptr_d[dst + 1];
    int swz = (dd & 7) << 3;
    for (int base0 = lo; base0 < hi; base0 += 64) {
      int n = min(64, hi - base0);
      int sv = 0, tv = 0;
      float iv = 0.0f;
      if (l < n) {
        uint2 se = esen[base0 + l];
        sv = (int)(se.x & 0xFFFFFu);
        tv = (int)(se.x >> 20);
        iv = 1.0f / (float)max(hist2[dst * RR + tv], 1);
      }
      int k4max = (n + 3) >> 2;
      for (int k4 = 0; k4 < k4max; ++k4) {
        int eid = k4 * 4 + eq;
        int s = __shfl(sv, eid);
        int ty = __shfl(tv, eid);
        float w = __shfl(iv, eid);
        if (eid < n) {
          uint2 v = *reinterpret_cast<const uint2*>(h_bf + (size_t)s * 64 + c4 * 4);
          float* sp = s_lds + (dd * 16 + ty) * 64 + ((c4 * 4) ^ swz);
          atomicAdd(sp + 0, b2f((unsigned short)(v.x & 0xffffu)) * w);
          atomicAdd(sp + 1, b2f((unsigned short)(v.x >> 16)) * w);
          atomicAdd(sp + 2, b2f((unsigned short)(v.y & 0xffffu)) * w);
          atomicAdd(sp + 3, b2f((unsigned short)(v.y >> 16)) * w);
        }
      }
    }
  }
  __syncthreads();
  // phase 2: acc = sum_r s_r @ W_r + h @ w2 ; wave wv owns true cols wv*16+m
  int m = l & 15, q = l >> 4, nt = wv;
  f32x4 acc = (f32x4){0.0f, 0.0f, 0.0f, 0.0f};
  {
    int swz = (m & 7) << 3;
    for (int r = 0; r < RR; ++r) {
      const unsigned short* Wr = Wt + (r << 12) + (nt * 16 + m) * 64 + q * 8;
      const float* arow = s_lds + (m * 16 + r) * 64;
#pragma unroll
      for (int s = 0; s < 2; ++s) {
        const float* ap = arow + ((s * 32 + q * 8) ^ swz);
        bf16x8 a;
#pragma unroll
        for (int j = 0; j < 8; ++j) a[j] = (short)f2b(ap[j]);
        bf16x8 b = *reinterpret_cast<const bf16x8*>(Wr + s * 32);
        acc = __builtin_amdgcn_mfma_f32_16x16x32_bf16(a, b, acc, 0, 0, 0);
      }
    }
  }
#pragma unroll
  for (int s = 0; s < 2; ++s) {
    bf16x8 a = *reinterpret_cast<const bf16x8*>(h_bf + (d0 + m) * 64 + s * 32 + q * 8);
    bf16x8 b = *reinterpret_cast<const bf16x8*>(w2t + (nt * 16 + m) * 64 + s * 32 + q * 8);
    acc = __builtin_amdgcn_mfma_f32_16x16x32_bf16(a, b, acc, 0, 0, 0);
  }
  float bb = b2[nt * 16 + m];
#pragma unroll
  for (int i = 0; i < 4; ++i) acc[i] += bb;
  // pooled epilogue: slot A = graph of dst d0; slot B = the next graph
  int c = nt * 16 + m;
  int gA;
  {
    int lo2 = 0, hi2 = GG;
    while (lo2 < hi2) {
      int mid = (lo2 + hi2) >> 1;
      if (bounds[mid] <= (int)d0) lo2 = mid + 1; else hi2 = mid;
    }
    gA = lo2;
  }
  int bndA = bounds[gA];   // end of graph gA
  float sA = 0.0f, xA = -3.4e38f, sB = 0.0f, xB = -3.4e38f;
#pragma unroll
  for (int i = 0; i < 4; ++i) {
    int row = (int)d0 + q * 4 + i;
    if (row < bndA) { sA += acc[i]; xA = fmaxf(xA, acc[i]); }
    else            { sB += acc[i]; xB = fmaxf(xB, acc[i]); }
  }
#pragma unroll
  for (int off = 16; off <= 32; off <<= 1) {
    sA += __shfl_xor(sA, off); xA = fmaxf(xA, __shfl_xor(xA, off));
    sB += __shfl_xor(sB, off); xB = fmaxf(xB, __shfl_xor(xB, off));
  }
  if (q == 0) {
    size_t base = (size_t)blockIdx.x * 128;
    psum_p[base + c] = sA;
    psum_p[base + 64 + c] = sB;
    pmax_p[base + c] = xA;
    pmax_p[base + 64 + c] = xB;
  }
}

// ---------------- fused pool(x) + block-partial(out) + MLP head + log_softmax ----------------
__global__ __launch_bounds__(256) void k_head(const float* x, const int* bounds,
    const float* psum_p, const float* pmax_p, const float* lin_w, const float* lin_b,
    const float* fc_w, const float* fc_b, float* dout) {
  __shared__ float4 psum[8][32], pmax[8][32];
  __shared__ float gsum[192], gmax[192];
  __shared__ float part[4][64];
  __shared__ float hid[HD], lg[CC], mred[2];
  int g = blockIdx.x, t = threadIdx.x;
  int lo = (g == 0) ? 0 : bounds[g - 1];
  int hi = bounds[g];
  int nn = hi - lo;
  {
    int c4 = t & 31, ch = t >> 5;   // 8 chunks x 32 col-groups over x's 128 cols
    int a = lo + (nn * ch) / 8, b = lo + (nn * (ch + 1)) / 8;
    float4 s = {0, 0, 0, 0};
    float4 mx = {-3.4e38f, -3.4e38f, -3.4e38f, -3.4e38f};
    const float* bp = x + (size_t)a * FD + c4 * 4;
    int n = a;
    for (; n + 4 <= b; n += 4) {
      float4 v0 = *reinterpret_cast<const float4*>(bp);
      float4 v1 = *reinterpret_cast<const float4*>(bp + FD);
      float4 v2 = *reinterpret_cast<const float4*>(bp + 2 * FD);
      float4 v3 = *reinterpret_cast<const float4*>(bp + 3 * FD);
      bp += 4 * FD;
      s.x += v0.x + v1.x + v2.x + v3.x;
      s.y += v0.y + v1.y + v2.y + v3.y;
      s.z += v0.z + v1.z + v2.z + v3.z;
      s.w += v0.w + v1.w + v2.w + v3.w;
      mx.x = fmaxf(fmaxf(fmaxf(mx.x, v0.x), fmaxf(v1.x, v2.x)), v3.x);
      mx.y = fmaxf(fmaxf(fmaxf(mx.y, v0.y), fmaxf(v1.y, v2.y)), v3.y);
      mx.z = fmaxf(fmaxf(fmaxf(mx.z, v0.z), fmaxf(v1.z, v2.z)), v3.z);
      mx.w = fmaxf(fmaxf(fmaxf(mx.w, v0.w), fmaxf(v1.w, v2.w)), v3.w);
    }
    for (; n < b; ++n) {
      float4 v = *reinterpret_cast<const float4*>(bp);
      bp += FD;
      s.x += v.x; s.y += v.y; s.z += v.z; s.w += v.w;
      mx.x = fmaxf(mx.x, v.x); mx.y = fmaxf(mx.y, v.y);
      mx.z = fmaxf(mx.z, v.z); mx.w = fmaxf(mx.w, v.w);
    }
    psum[ch][c4] = s;
    pmax[ch][c4] = mx;
  }
  __syncthreads();
  if (t < 32) {
    float4 s = psum[0][t], m = pmax[0][t];
#pragma unroll
    for (int ch = 1; ch < 8; ++ch) {
      float4 ps = psum[ch][t], pm = pmax[ch][t];
      s.x += ps.x; s.y += ps.y; s.z += ps.z; s.w += ps.w;
      m.x = fmaxf(m.x, pm.x); m.y = fmaxf(m.y, pm.y);
      m.z = fmaxf(m.z, pm.z); m.w = fmaxf(m.w, pm.w);
    }
    gsum[t * 4 + 0] = s.x; gsum[t * 4 + 1] = s.y;
    gsum[t * 4 + 2] = s.z; gsum[t * 4 + 3] = s.w;
    gmax[t * 4 + 0] = m.x; gmax[t * 4 + 1] = m.y;
    gmax[t * 4 + 2] = m.z; gmax[t * 4 + 3] = m.w;
  } else if (t < 96) {
    // out pools: 16-row blocks
    int c = t - 32;
    int blo = lo >> 4, bhi = (hi - 1) >> 4;
    float s = 0.0f, mx = -3.4e38f;
    for (int b = blo; b <= bhi; ++b) {
      size_t base = (size_t)b * 128;
      if (b * 16 >= lo) {          // slot A belongs to g
        s += psum_p[base + c];
        mx = fmaxf(mx, pmax_p[base + c]);
      }
      if (b * 16 + 15 < hi) {      // slot B belongs to g (or empty: +0 / -inf)
        s += psum_p[base + 64 + c];
        mx = fmaxf(mx, pmax_p[base + 64 + c]);
      }
    }
    gsum[128 + c] = s;
    gmax[128 + c] = mx;
  }
  __syncthreads();
  {
    int o = t & 63, pp = t >> 6;
    float a = 0.0f;
    int k0 = pp * 96;
    for (int k = k0; k < k0 + 96; ++k) {
      float gv = (k < 192) ? gsum[k] : gmax[k - 192];
      a += gv * lin_w[k * 64 + o];
    }
    part[pp][o] = a;
  }
  __syncthreads();
  if (t < HD) {
    float a = lin_b[t] + part[0][t] + part[1][t] + part[2][t] + part[3][t];
    hid[t] = fmaxf(a, 0.0f);
  }
  __syncthreads();
  if (t < CC) {
    float a = fc_b[t];
    for (int k = 0; k < HD; ++k) a += hid[k] * fc_w[k * CC + t];
    lg[t] = a;
  }
  __syncthreads();
  if (t == 0) {
    float mm = lg[0];
#pragma unroll
    for (int i = 1; i < CC; ++i) mm = fmaxf(mm, lg[i]);
    float se = 0.0f;
#pragma unroll
    for (int i = 0; i < CC; ++i) se += __expf(lg[i] - mm);
    mred[0] = mm;
    mred[1] = __logf(se);
  }
  __syncthreads();
  if (t < CC) dout[g * CC + t] = lg[t] - mred[0] - mred[1];
}

extern "C" void kernel_launch(void* const* d_in, const int* in_sizes, int n_in,
                              void* d_out, int out_size, void* d_ws, size_t ws_size,
                              hipStream_t stream) {
  const float* x     = (const float*)d_in[0];
  const int* ei      = (const int*)d_in[1];
  const float* enorm = (const float*)d_in[2];
  const int* etype   = (const int*)d_in[3];
  const int* seq     = (const int*)d_in[4];
  const float* w1_rel  = (const float*)d_in[6];
  const float* w1_root = (const float*)d_in[7];
  const float* b1      = (const float*)d_in[8];
  const float* bases   = (const float*)d_in[9];
  const float* comp    = (const float*)d_in[10];
  const float* w2      = (const float*)d_in[11];
  const float* b2      = (const float*)d_in[12];
  const float* lin_w   = (const float*)d_in[13];
  const float* lin_b   = (const float*)d_in[14];
  const float* fc_w    = (const float*)d_in[15];
  const float* fc_b    = (const float*)d_in[16];
  float* dout = (float*)d_out;

  char* p = (char*)d_ws;
  unsigned short* hroot_bf = (unsigned short*)p; p += (size_t)NN * 64 * 2;  // 12.8 MB
  unsigned short* xw_bf    = (unsigned short*)p; p += (size_t)NN * 64 * 2;  // 12.8 MB
  unsigned short* h_bf = (unsigned short*)p; p += (size_t)NN * 64 * 2;      // 12.8 MB
  unsigned short* Wt   = (unsigned short*)p; p += (size_t)RR * 4096 * 2;
  unsigned short* wcat2 = (unsigned short*)p; p += (size_t)128 * 128 * 2;
  unsigned short* w2t  = (unsigned short*)p; p += (size_t)64 * 64 * 2;
  uint2* esen  = (uint2*)p; p += (size_t)NE * 8;        // 4 MB
  int* hist2   = (int*)p; p += (size_t)NN * RR * 4;     // 6.4 MB (zero region)
  float* psum_p = (float*)p; p += (size_t)NOBLK * 128 * 4;  // 3.2 MB [block][2][64]
  float* pmax_p = (float*)p; p += (size_t)NOBLK * 128 * 4;  // 3.2 MB
  int* rowptr_d = (int*)p; p += (size_t)(NDBLK * 256) * 4;  // 400 KB (NN+1 used)
  int* ctr_d   = (int*)p; p += (size_t)(NDBLK * 256) * 4;   // 400 KB (NN+1 used)
  int* bsum    = (int*)p; p += (size_t)NGROUP * 4;
  int* bounds  = (int*)p; p += (size_t)GG * 4;

  hipLaunchKernelGGL(k_prep, dim3(337 + ZBLK), dim3(256), 0, stream,
                     comp, bases, w1_root, w1_rel, w2, seq, Wt, wcat2, w2t, hist2, bounds);
  hipLaunchKernelGGL(k_projhists, dim3(NBLK + NPBLK), dim3(256), 0, stream,
                     x, wcat2, b1, hroot_bf, xw_bf, ei, etype, hist2);
  hipLaunchKernelGGL(k_scanA, dim3(NDBLK), dim3(256), 0, stream, hist2, bsum);
  hipLaunchKernelGGL(k_bsum, dim3(1), dim3(256), 0, stream, bsum);
  hipLaunchKernelGGL(k_scanC, dim3(NDBLK), dim3(256), 0, stream, hist2, bsum, rowptr_d, ctr_d);
  hipLaunchKernelGGL(k_sort, dim3(NBLK), dim3(256), 0, stream,
                     ei, etype, enorm, ctr_d, esen);
  hipLaunchKernelGGL(k_gconv_seg, dim3(NN / 4), dim3(256), 0, stream,
                     rowptr_d, esen, xw_bf, hroot_bf, h_bf);
  hipLaunchKernelGGL(k_out, dim3(NOBLK), dim3(256), 0, stream,
                     rowptr_d, esen, hist2, h_bf, Wt, w2t, b2, bounds, psum_p, pmax_p);
  hipLaunchKernelGGL(k_head, dim3(GG), dim3(256), 0, stream, x, bounds,
                     psum_p, pmax_p, lin_w, lin_b, fc_w, fc_b, dout);
}

// Round 12
// 327.419 us; speedup vs baseline: 1.7128x; 1.7128x over previous
//
#include <hip/hip_runtime.h>
#include <hip/hip_bf16.h>

#define NN 100000   // nodes
#define NE 500000   // edges
#define FD 128      // input features
#define HD 64       // hidden
#define RR 16       // relations
#define NBASE 30    // bases
#define GG 1000     // graphs
#define CC 10       // classes
#define NGROUP 6250 // NN/16
#define NBLK ((NE + 255) / 256)   // 1954 edge-blocks
#define NDBLK ((NN + 256) / 256)  // 391 dst-scan blocks (covers NN+1 cells)
#define NOBLK (NN / 16)           // 6250 k_out blocks
#define NPBLK ((NGROUP + 3) / 4)  // 1563 proj blocks (64 rows each)
#define TOTZ (NN * RR)            // ints zeroed in k_prep tail: hist2 only
#define ZBLK ((TOTZ + 1023) / 1024)

// Per-node 64-vectors (hroot_bf, xw_bf, h_bf, y_bf) are stored sigma-order:
// stored[(c&15)*4 + (c>>4)] = true[c] (MFMA C-layout interleave). Wt/w2t have
// contraction dim sigma-permuted to match.
// wcat2 is stored in MFMA B-fragment order: [(nt*4+s)][lane l=q*16+m][8 bf16].
// Edge ordering: pos slots are per-dst (arrival order); 1/cnt(dst,r) from hist2.
// out[] pooling: k_out emits atomic-free block-partials psum_p/pmax_p
// [NOBLK][2][64] (a 16-dst block spans <=2 graphs); k_head reassembles graph g
// (slot A iff blockstart >= lo, slot B iff blockend < hi; empty slots are
// 0/-inf so over-inclusion is harmless). x is pooled directly in k_head.
// k_projhists fuses the independent hists (blocks 0..NBLK-1, dispatched first:
// they feed scanA next) and proj (blocks NBLK..) workloads into one launch.
// NOTE (R11 lesson): dst-major RGCN with LDS-atomic per-(dst,type) aggregation
// is 8x slower than this edge-major y round-trip (6.2e7 LDS bank conflicts).

typedef __attribute__((ext_vector_type(8))) short bf16x8;
typedef __attribute__((ext_vector_type(4))) float f32x4;

__device__ inline unsigned short f2b(float x) {
  __hip_bfloat16 b = __float2bfloat16(x);
  return *reinterpret_cast<unsigned short*>(&b);
}
__device__ inline float b2f(unsigned short u) {
  return __uint_as_float(((unsigned)u) << 16);
}
__device__ inline unsigned pk2(float a, float b) {
  return (unsigned)f2b(a) | ((unsigned)f2b(b) << 16);
}

__device__ inline int block_scan_incl(int v, int* ps, int t) {
  ps[t] = v;
  __syncthreads();
  for (int off = 1; off < 256; off <<= 1) {
    int u = (t >= off) ? ps[t - off] : 0;
    __syncthreads();
    ps[t] += u;
    __syncthreads();
  }
  return ps[t];
}

// ---------------- fused prep: Wt + wcat2 + w2t + bounds + zero(hist2) ----------------
__global__ void k_prep(const float* comp, const float* bases, const float* w_root,
                       const float* w_rel, const float* w2, const int* seq,
                       unsigned short* Wt, unsigned short* wcat2, unsigned short* w2t,
                       int* zbase, int* bounds) {
  int bx = blockIdx.x;
  if (bx < 256) {
    int idx = bx * 256 + threadIdx.x;  // r*4096 + k*64 + n
    int r = idx >> 12, kj = idx & 4095;
    int k = kj >> 6, n = kj & 63;
    float acc = 0.0f;
    for (int b = 0; b < NBASE; ++b)
      acc += comp[r * NBASE + b] * bases[b * 4096 + kj];
    int sk = (k & 15) * 4 + (k >> 4);
    Wt[(r << 12) + n * 64 + sk] = f2b(acc);
  } else if (bx < 336) {
    int idx = (bx - 256) * 256 + threadIdx.x;
    if (idx < 16384) {
      int n = idx >> 7, k = idx & 127;   // n: output col 0..127, k: input 0..127
      float v = (n < 64) ? w_root[k * 64 + n] : w_rel[k * 64 + (n - 64)];
      int nt = n >> 4, m = n & 15;
      int s = k >> 5, q = (k >> 3) & 3, j = k & 7;
      wcat2[(((nt * 4 + s) * 64) + q * 16 + m) * 8 + j] = f2b(v);
    } else if (idx < 16384 + 4096) {
      int i2 = idx - 16384;
      int n = i2 >> 6, k = i2 & 63;
      int sk = (k & 15) * 4 + (k >> 4);
      w2t[n * 64 + sk] = f2b(w2[k * 64 + n]);
    }
  } else if (bx == 336) {
    // bounds = inclusive cumsum of seq (1000), 250 threads x 4
    __shared__ int ps[256];
    int t = threadIdx.x;
    int loc[4];
    int ss = 0;
    if (t < 250) {
      for (int i = 0; i < 4; ++i) { loc[i] = seq[t * 4 + i]; ss += loc[i]; }
    }
    int incl = block_scan_incl(ss, ps, t);
    int base = incl - ss;
    if (t < 250) {
      int run = base;
      for (int i = 0; i < 4; ++i) { run += loc[i]; bounds[t * 4 + i] = run; }
    }
  } else {
    // zero hist2 (NN*RR ints), 1024 ints per block via int4
    int idx = (bx - 337) * 1024 + threadIdx.x * 4;
    if (idx < TOTZ)
      *reinterpret_cast<int4*>(zbase + idx) = make_int4(0, 0, 0, 0);
  }
}

// ---------------- fused: hists (blocks 0..NBLK-1) + proj MFMA (blocks NBLK..) ----------
__global__ __launch_bounds__(256) void k_projhists(
    const float* x, const unsigned short* wcat2, const float* b1,
    unsigned short* hroot_bf, unsigned short* xw_bf,
    const int* ei, const int* etype, int* bch, int* hist2) {
  __shared__ unsigned short wsh[16384];  // 32 KB, fragment-ordered (proj branch)
  __shared__ int lh[RR];                 // hists branch
  if (blockIdx.x < NBLK) {
    // ---- hists: per-block type counts + per-(dst,type) histogram ----
    if (threadIdx.x < RR) lh[threadIdx.x] = 0;
    __syncthreads();
    int e = blockIdx.x * 256 + threadIdx.x;
    if (e < NE) {
      int t = etype[e];
      atomicAdd(&lh[t], 1);
      atomicAdd(&hist2[ei[NE + e] * RR + t], 1);
    }
    __syncthreads();
    if (threadIdx.x < RR) bch[blockIdx.x * RR + threadIdx.x] = lh[threadIdx.x];
    return;
  }
  // ---- proj: hroot_bf / xw_bf (sigma), LDS-staged weights ----
  int bx = blockIdx.x - NBLK;
  int wv = threadIdx.x >> 6, l = threadIdx.x & 63, m = l & 15, q = l >> 4;
  int g = bx * 4 + wv;
  bool active = (g < NGROUP);
  int gc = active ? g : (NGROUP - 1);   // clamp so OOB waves still reach barrier
  size_t n0 = (size_t)gc * 16;
  const float* xr = x + (n0 + m) * FD + q * 8;
  float4 xv[8];
#pragma unroll
  for (int s = 0; s < 4; ++s) {
    xv[2 * s] = *reinterpret_cast<const float4*>(xr + s * 32);
    xv[2 * s + 1] = *reinterpret_cast<const float4*>(xr + s * 32 + 4);
  }
  // stage weights -> LDS (32 KB), 256 threads x 16B x 8 rounds
  {
    const uint4* wsrc = reinterpret_cast<const uint4*>(wcat2);
    uint4* wdst = reinterpret_cast<uint4*>(wsh);
#pragma unroll
    for (int r = 0; r < 8; ++r)
      wdst[r * 256 + threadIdx.x] = wsrc[r * 256 + threadIdx.x];
  }
  __syncthreads();
  if (!active) return;   // no barriers after this point
  bf16x8 afr[4];
#pragma unroll
  for (int s = 0; s < 4; ++s) {
    float4 xa = xv[2 * s], xb = xv[2 * s + 1];
    bf16x8 a;
    a[0] = (short)f2b(xa.x); a[1] = (short)f2b(xa.y);
    a[2] = (short)f2b(xa.z); a[3] = (short)f2b(xa.w);
    a[4] = (short)f2b(xb.x); a[5] = (short)f2b(xb.y);
    a[6] = (short)f2b(xb.z); a[7] = (short)f2b(xb.w);
    afr[s] = a;
  }
  f32x4 acc[8];
#pragma unroll
  for (int nt = 0; nt < 8; ++nt) acc[nt] = (f32x4){0, 0, 0, 0};
#pragma unroll
  for (int s = 0; s < 4; ++s) {
#pragma unroll
    for (int nt = 0; nt < 8; ++nt) {
      bf16x8 b = *reinterpret_cast<const bf16x8*>(wsh + (size_t)((nt * 4 + s) * 64 + l) * 8);
      acc[nt] = __builtin_amdgcn_mfma_f32_16x16x32_bf16(afr[s], b, acc[nt], 0, 0, 0);
    }
  }
  float bv[4];
#pragma unroll
  for (int nt = 0; nt < 4; ++nt) bv[nt] = b1[nt * 16 + m];
#pragma unroll
  for (int i = 0; i < 4; ++i) {
    size_t row = (n0 + q * 4 + i) * 64 + m * 4;  // sigma: stored = m*4 + nt
    uint2 oh, ox;
    oh.x = pk2(acc[0][i] + bv[0], acc[1][i] + bv[1]);
    oh.y = pk2(acc[2][i] + bv[2], acc[3][i] + bv[3]);
    ox.x = pk2(acc[4][i], acc[5][i]);
    ox.y = pk2(acc[6][i], acc[7][i]);
    *reinterpret_cast<uint2*>(hroot_bf + row) = oh;
    *reinterpret_cast<uint2*>(xw_bf + row) = ox;
  }
}

// ---------------- per-dst scan (391 blocks over NN+1 cells) ----------------
__device__ inline int dst_degree(const int* hist2, int dst) {
  const int4* hp = reinterpret_cast<const int4*>(hist2 + dst * RR);
  int4 a = hp[0], b = hp[1], c = hp[2], d = hp[3];
  return a.x + a.y + a.z + a.w + b.x + b.y + b.z + b.w +
         c.x + c.y + c.z + c.w + d.x + d.y + d.z + d.w;
}

__global__ void k_scanA(const int* hist2, int* bsum) {
  __shared__ int red[256];
  int t = threadIdx.x;
  int dst = blockIdx.x * 256 + t;
  red[t] = (dst < NN) ? dst_degree(hist2, dst) : 0;
  __syncthreads();
  for (int s = 128; s; s >>= 1) {
    if (t < s) red[t] += red[t + s];
    __syncthreads();
  }
  if (t == 0) bsum[blockIdx.x] = red[0];
}

__global__ void k_scanC(const int* hist2, const int* bsum, int* rowptr_d, int* ctr_d) {
  int t = threadIdx.x;
  int dst = blockIdx.x * 256 + t;
  int v = (dst < NN) ? dst_degree(hist2, dst) : 0;
  __shared__ int ps[256];
  int incl = block_scan_incl(v, ps, t);
  int ex = bsum[blockIdx.x] + incl - v;
  if (dst <= NN) { rowptr_d[dst] = ex; ctr_d[dst] = ex; }
}

// ---------------- bscan: bsum exclusive-scan + bbase per-block type bases + offs ----
__global__ void k_bscan(const int* bch, int* bsum, int* bbase, int* offs) {
  __shared__ int part[16][17], chunkbase[16][17];
  __shared__ int colbase[16];
  __shared__ int ps[256];
  int t = threadIdx.x;
  // --- A: exclusive scan of bsum[0..NDBLK)
  {
    int i0 = t * 2, i1 = t * 2 + 1;
    int l0 = (i0 < NDBLK) ? bsum[i0] : 0;
    int l1 = (i1 < NDBLK) ? bsum[i1] : 0;
    int sa = l0 + l1;
    int incla = block_scan_incl(sa, ps, t);
    int run = incla - sa;
    if (i0 < NDBLK) bsum[i0] = run;
    run += l0;
    if (i1 < NDBLK) bsum[i1] = run;
  }
  __syncthreads();
  // --- B: per-block type bases over bch
  int ty = t & 15, ck = t >> 4;
  const int CH = (NBLK + 15) / 16;
  int b0 = ck * CH, b1 = min(b0 + CH, NBLK);
  int s = 0;
  for (int b = b0; b < b1; ++b) s += bch[b * 16 + ty];
  part[ck][ty] = s;
  __syncthreads();
  if (t < 16) {
    int run = 0;
    for (int c = 0; c < 16; ++c) { chunkbase[c][t] = run; run += part[c][t]; }
    colbase[t] = run;  // column total
  }
  __syncthreads();
  if (t == 0) {
    int run = 0;
    for (int r = 0; r < RR; ++r) { int v = colbase[r]; offs[r] = run; colbase[r] = run; run += v; }
    offs[RR] = run;
  }
  __syncthreads();
  {
    int run = colbase[ty] + chunkbase[ck][ty];
    for (int b = b0; b < b1; ++b) {
      int v = bch[b * 16 + ty];
      bbase[b * 16 + ty] = run;
      run += v;
    }
  }
}

// ---------------- sort: per-dst pos slots; inv from hist2 ----------------
// tse[p] = {src, inv_bits, pos, 0} at type-order slot; esen[pos] = {src, norm} at dst slot.
__global__ void k_sort(const int* ei, const int* etype, const float* enorm,
                       const int* bbase, const int* hist2, int* ctr_d,
                       uint4* tse, uint2* esen) {
  __shared__ int lcnt[RR];
  if (threadIdx.x < RR) lcnt[threadIdx.x] = 0;
  __syncthreads();
  int e = blockIdx.x * 256 + threadIdx.x;
  if (e >= NE) return;
  int t = etype[e];
  int rank = atomicAdd(&lcnt[t], 1);          // LDS, block-local
  int p = bbase[blockIdx.x * RR + t] + rank;  // deterministic base (cached read)
  int src = ei[e];
  int dst = ei[NE + e];
  int cnt = hist2[dst * RR + t];              // L2-resident gather
  float inv = 1.0f / (float)max(cnt, 1);
  int pos = atomicAdd(&ctr_d[dst], 1);        // random, low-contention
  esen[pos] = make_uint2((unsigned)src, __float_as_uint(enorm[e]));
  tse[p] = make_uint4((unsigned)src, __float_as_uint(inv), (unsigned)pos, 0u);
}

// ---------------- GraphConv segment-sum: 4 edges/iter, uint2 loads (sigma space) ----------------
__global__ __launch_bounds__(256) void k_gconv_seg(const int* rowptr_d, const uint2* esen,
    const unsigned short* xw_bf, const unsigned short* hroot_bf, unsigned short* h_bf) {
  int wv = threadIdx.x >> 6, l = threadIdx.x & 63;
  int c4 = l & 15, eq = l >> 4;
  int dst = blockIdx.x * 4 + wv;
  int lo = rowptr_d[dst];
  int hi = rowptr_d[dst + 1];
  float4 acc = {0.0f, 0.0f, 0.0f, 0.0f};
  for (int base0 = lo; base0 < hi; base0 += 64) {
    int n = min(64, hi - base0);
    int sv = 0;
    float nv = 0.0f;
    if (l < n) {
      uint2 se = esen[base0 + l];
      sv = (int)se.x;
      nv = __uint_as_float(se.y);
    }
    int k4max = (n + 3) >> 2;
    for (int k4 = 0; k4 < k4max; ++k4) {
      int eid = k4 * 4 + eq;
      int s = __shfl(sv, eid);
      float w = __shfl(nv, eid);
      if (eid < n) {
        uint2 v = *reinterpret_cast<const uint2*>(xw_bf + (size_t)s * 64 + c4 * 4);
        acc.x += b2f((unsigned short)(v.x & 0xffffu)) * w;
        acc.y += b2f((unsigned short)(v.x >> 16)) * w;
        acc.z += b2f((unsigned short)(v.y & 0xffffu)) * w;
        acc.w += b2f((unsigned short)(v.y >> 16)) * w;
      }
    }
  }
  acc.x += __shfl_xor(acc.x, 16); acc.y += __shfl_xor(acc.y, 16);
  acc.z += __shfl_xor(acc.z, 16); acc.w += __shfl_xor(acc.w, 16);
  acc.x += __shfl_xor(acc.x, 32); acc.y += __shfl_xor(acc.y, 32);
  acc.z += __shfl_xor(acc.z, 32); acc.w += __shfl_xor(acc.w, 32);
  if (l < 16) {
    uint2 hb = *reinterpret_cast<const uint2*>(hroot_bf + (size_t)dst * 64 + l * 4);
    acc.x += b2f((unsigned short)(hb.x & 0xffffu));
    acc.y += b2f((unsigned short)(hb.x >> 16));
    acc.z += b2f((unsigned short)(hb.y & 0xffffu));
    acc.w += b2f((unsigned short)(hb.y >> 16));
    uint2 o;
    o.x = pk2(acc.x, acc.y);
    o.y = pk2(acc.z, acc.w);
    *reinterpret_cast<uint2*>(h_bf + (size_t)dst * 64 + l * 4) = o;
  }
}

// ---------------- RGCN via MFMA; y rows at dst-ordered slots, sigma uint2 stores ----------------
__global__ __launch_bounds__(256) void k_rgcn_y(const uint4* tse, const int* offs,
    const unsigned short* h_bf, const unsigned short* Wt, unsigned short* y_bf) {
  int r = blockIdx.x;
  int lo = offs[r], hi = offs[r + 1];
  int cnt = hi - lo;
  int wv = threadIdx.x >> 6;
  int l = threadIdx.x & 63;
  int m = l & 15, q = l >> 4;
  int ngroups = (cnt + 15) / 16;
  const unsigned short* Wr = Wt + (r << 12);
  bf16x8 bfr[2][4];
#pragma unroll
  for (int s = 0; s < 2; ++s)
#pragma unroll
    for (int nt = 0; nt < 4; ++nt)
      bfr[s][nt] = *reinterpret_cast<const bf16x8*>(Wr + (nt * 16 + m) * 64 + s * 32 + q * 8);

  for (int g = blockIdx.y * 4 + wv; g < ngroups; g += gridDim.y * 4) {
    int base = lo + g * 16;
    int ne = min(16, hi - base);
    int p = base + ((m < ne) ? m : 0);
    uint4 t4 = tse[p];
    int src = (int)t4.x;
    float inv = __uint_as_float(t4.y);
    int pos = (int)t4.z;
    f32x4 acc[4];
#pragma unroll
    for (int nt = 0; nt < 4; ++nt) acc[nt] = (f32x4){0, 0, 0, 0};
    const unsigned short* hrow = h_bf + (size_t)src * 64 + q * 8;
#pragma unroll
    for (int s = 0; s < 2; ++s) {
      bf16x8 afr = *reinterpret_cast<const bf16x8*>(hrow + s * 32);
#pragma unroll
      for (int nt = 0; nt < 4; ++nt)
        acc[nt] = __builtin_amdgcn_mfma_f32_16x16x32_bf16(afr, bfr[s][nt], acc[nt], 0, 0, 0);
    }
#pragma unroll
    for (int i = 0; i < 4; ++i) {
      int row = q * 4 + i;
      float ir = __shfl(inv, row);
      int pr = __shfl(pos, row);
      if (row < ne) {
        uint2 o;
        o.x = pk2(acc[0][i] * ir, acc[1][i] * ir);
        o.y = pk2(acc[2][i] * ir, acc[3][i] * ir);
        *reinterpret_cast<uint2*>(y_bf + (size_t)pr * 64 + m * 4) = o;
      }
    }
  }
}

// ---------------- fused: row = h@w2 + b2 + sum(y rows); block-partial pooled sum/max ----------------
__global__ __launch_bounds__(256) void k_out(const int* rowptr_d, const unsigned short* y_bf,
    const unsigned short* h_bf, const unsigned short* w2t, const float* b2,
    const int* bounds, float* psum_p, float* pmax_p) {
  __shared__ float ldsC[16][68];   // [dst-in-block][sigma col]
  __shared__ int gidv[16];
  int wv = threadIdx.x >> 6, l = threadIdx.x & 63;
  int c4 = l & 15, eq = l >> 4;
  size_t d0 = (size_t)blockIdx.x * 16;
  // graph ids for the 16 dsts (binary search over bounds), overlapped with phase 1
  if (threadIdx.x < 16) {
    int dst = (int)d0 + threadIdx.x;
    int lo2 = 0, hi2 = GG;
    while (lo2 < hi2) {
      int mid = (lo2 + hi2) >> 1;
      if (bounds[mid] <= dst) lo2 = mid + 1; else hi2 = mid;
    }
    gidv[threadIdx.x] = lo2;
  }
  for (int dd = 0; dd < 4; ++dd) {
    int dst = (int)d0 + wv * 4 + dd;
    int lo = rowptr_d[dst];
    int hi = rowptr_d[dst + 1];
    float4 acc = {0.0f, 0.0f, 0.0f, 0.0f};
    for (int row = lo + eq; row < hi; row += 4) {
      uint2 v = *reinterpret_cast<const uint2*>(y_bf + (size_t)row * 64 + c4 * 4);
      acc.x += b2f((unsigned short)(v.x & 0xffffu));
      acc.y += b2f((unsigned short)(v.x >> 16));
      acc.z += b2f((unsigned short)(v.y & 0xffffu));
      acc.w += b2f((unsigned short)(v.y >> 16));
    }
    acc.x += __shfl_xor(acc.x, 16); acc.y += __shfl_xor(acc.y, 16);
    acc.z += __shfl_xor(acc.z, 16); acc.w += __shfl_xor(acc.w, 16);
    acc.x += __shfl_xor(acc.x, 32); acc.y += __shfl_xor(acc.y, 32);
    acc.z += __shfl_xor(acc.z, 32); acc.w += __shfl_xor(acc.w, 32);
    if (l < 16)
      *reinterpret_cast<float4*>(&ldsC[wv * 4 + dd][l * 4]) = acc;
  }
  __syncthreads();
  // phase 2: wave wv owns true cols wv*16 + m; y-sum for that col is at sigma m*4+wv
  int m = l & 15, q = l >> 4, nt = wv;
  float bb = b2[nt * 16 + m];
  f32x4 acc;
#pragma unroll
  for (int i = 0; i < 4; ++i) acc[i] = ldsC[q * 4 + i][m * 4 + nt] + bb;
#pragma unroll
  for (int s = 0; s < 2; ++s) {
    bf16x8 a = *reinterpret_cast<const bf16x8*>(h_bf + (d0 + m) * 64 + s * 32 + q * 8);
    bf16x8 b = *reinterpret_cast<const bf16x8*>(w2t + (nt * 16 + m) * 64 + s * 32 + q * 8);
    acc = __builtin_amdgcn_mfma_f32_16x16x32_bf16(a, b, acc, 0, 0, 0);
  }
  // pooled epilogue: slot A = graph of dst d0, slot B = graph of dst d0+15
  int c = nt * 16 + m;
  int gA = gidv[0];
  float sA = 0.0f, xA = -3.4e38f, sB = 0.0f, xB = -3.4e38f;
#pragma unroll
  for (int i = 0; i < 4; ++i) {
    int gi = gidv[q * 4 + i];
    if (gi == gA) { sA += acc[i]; xA = fmaxf(xA, acc[i]); }
    else          { sB += acc[i]; xB = fmaxf(xB, acc[i]); }
  }
#pragma unroll
  for (int off = 16; off <= 32; off <<= 1) {
    sA += __shfl_xor(sA, off); xA = fmaxf(xA, __shfl_xor(xA, off));
    sB += __shfl_xor(sB, off); xB = fmaxf(xB, __shfl_xor(xB, off));
  }
  if (q == 0) {
    size_t base = (size_t)blockIdx.x * 128;
    psum_p[base + c] = sA;
    psum_p[base + 64 + c] = sB;
    pmax_p[base + c] = xA;
    pmax_p[base + 64 + c] = xB;
  }
}

// ---------------- fused pool(x) + block-partial(out) + MLP head + log_softmax ----------------
__global__ __launch_bounds__(256) void k_head(const float* x, const int* bounds,
    const float* psum_p, const float* pmax_p, const float* lin_w, const float* lin_b,
    const float* fc_w, const float* fc_b, float* dout) {
  __shared__ float4 psum[8][32], pmax[8][32];
  __shared__ float gsum[192], gmax[192];
  __shared__ float part[4][64];
  __shared__ float hid[HD], lg[CC], mred[2];
  int g = blockIdx.x, t = threadIdx.x;
  int lo = (g == 0) ? 0 : bounds[g - 1];
  int hi = bounds[g];
  int nn = hi - lo;
  {
    int c4 = t & 31, ch = t >> 5;   // 8 chunks x 32 col-groups over x's 128 cols
    int a = lo + (nn * ch) / 8, b = lo + (nn * (ch + 1)) / 8;
    float4 s = {0, 0, 0, 0};
    float4 mx = {-3.4e38f, -3.4e38f, -3.4e38f, -3.4e38f};
    const float* bp = x + (size_t)a * FD + c4 * 4;
    int n = a;
    for (; n + 4 <= b; n += 4) {
      float4 v0 = *reinterpret_cast<const float4*>(bp);
      float4 v1 = *reinterpret_cast<const float4*>(bp + FD);
      float4 v2 = *reinterpret_cast<const float4*>(bp + 2 * FD);
      float4 v3 = *reinterpret_cast<const float4*>(bp + 3 * FD);
      bp += 4 * FD;
      s.x += v0.x + v1.x + v2.x + v3.x;
      s.y += v0.y + v1.y + v2.y + v3.y;
      s.z += v0.z + v1.z + v2.z + v3.z;
      s.w += v0.w + v1.w + v2.w + v3.w;
      mx.x = fmaxf(fmaxf(fmaxf(mx.x, v0.x), fmaxf(v1.x, v2.x)), v3.x);
      mx.y = fmaxf(fmaxf(fmaxf(mx.y, v0.y), fmaxf(v1.y, v2.y)), v3.y);
      mx.z = fmaxf(fmaxf(fmaxf(mx.z, v0.z), fmaxf(v1.z, v2.z)), v3.z);
      mx.w = fmaxf(fmaxf(fmaxf(mx.w, v0.w), fmaxf(v1.w, v2.w)), v3.w);
    }
    for (; n < b; ++n) {
      float4 v = *reinterpret_cast<const float4*>(bp);
      bp += FD;
      s.x += v.x; s.y += v.y; s.z += v.z; s.w += v.w;
      mx.x = fmaxf(mx.x, v.x); mx.y = fmaxf(mx.y, v.y);
      mx.z = fmaxf(mx.z, v.z); mx.w = fmaxf(mx.w, v.w);
    }
    psum[ch][c4] = s;
    pmax[ch][c4] = mx;
  }
  __syncthreads();
  if (t < 32) {
    float4 s = psum[0][t], m = pmax[0][t];
#pragma unroll
    for (int ch = 1; ch < 8; ++ch) {
      float4 ps = psum[ch][t], pm = pmax[ch][t];
      s.x += ps.x; s.y += ps.y; s.z += ps.z; s.w += ps.w;
      m.x = fmaxf(m.x, pm.x); m.y = fmaxf(m.y, pm.y);
      m.z = fmaxf(m.z, pm.z); m.w = fmaxf(m.w, pm.w);
    }
    gsum[t * 4 + 0] = s.x; gsum[t * 4 + 1] = s.y;
    gsum[t * 4 + 2] = s.z; gsum[t * 4 + 3] = s.w;
    gmax[t * 4 + 0] = m.x; gmax[t * 4 + 1] = m.y;
    gmax[t * 4 + 2] = m.z; gmax[t * 4 + 3] = m.w;
  } else if (t < 96) {
    // out pools: 16-row blocks
    int c = t - 32;
    int blo = lo >> 4, bhi = (hi - 1) >> 4;
    float s = 0.0f, mx = -3.4e38f;
    for (int b = blo; b <= bhi; ++b) {
      size_t base = (size_t)b * 128;
      if (b * 16 >= lo) {          // slot A belongs to g
        s += psum_p[base + c];
        mx = fmaxf(mx, pmax_p[base + c]);
      }
      if (b * 16 + 15 < hi) {      // slot B belongs to g (or empty: +0 / -inf)
        s += psum_p[base + 64 + c];
        mx = fmaxf(mx, pmax_p[base + 64 + c]);
      }
    }
    gsum[128 + c] = s;
    gmax[128 + c] = mx;
  }
  __syncthreads();
  {
    int o = t & 63, pp = t >> 6;
    float a = 0.0f;
    int k0 = pp * 96;
    for (int k = k0; k < k0 + 96; ++k) {
      float gv = (k < 192) ? gsum[k] : gmax[k - 192];
      a += gv * lin_w[k * 64 + o];
    }
    part[pp][o] = a;
  }
  __syncthreads();
  if (t < HD) {
    float a = lin_b[t] + part[0][t] + part[1][t] + part[2][t] + part[3][t];
    hid[t] = fmaxf(a, 0.0f);
  }
  __syncthreads();
  if (t < CC) {
    float a = fc_b[t];
    for (int k = 0; k < HD; ++k) a += hid[k] * fc_w[k * CC + t];
    lg[t] = a;
  }
  __syncthreads();
  if (t == 0) {
    float mm = lg[0];
#pragma unroll
    for (int i = 1; i < CC; ++i) mm = fmaxf(mm, lg[i]);
    float se = 0.0f;
#pragma unroll
    for (int i = 0; i < CC; ++i) se += __expf(lg[i] - mm);
    mred[0] = mm;
    mred[1] = __logf(se);
  }
  __syncthreads();
  if (t < CC) dout[g * CC + t] = lg[t] - mred[0] - mred[1];
}

extern "C" void kernel_launch(void* const* d_in, const int* in_sizes, int n_in,
                              void* d_out, int out_size, void* d_ws, size_t ws_size,
                              hipStream_t stream) {
  const float* x     = (const float*)d_in[0];
  const int* ei      = (const int*)d_in[1];
  const float* enorm = (const float*)d_in[2];
  const int* etype   = (const int*)d_in[3];
  const int* seq     = (const int*)d_in[4];
  const float* w1_rel  = (const float*)d_in[6];
  const float* w1_root = (const float*)d_in[7];
  const float* b1      = (const float*)d_in[8];
  const float* bases   = (const float*)d_in[9];
  const float* comp    = (const float*)d_in[10];
  const float* w2      = (const float*)d_in[11];
  const float* b2      = (const float*)d_in[12];
  const float* lin_w   = (const float*)d_in[13];
  const float* lin_b   = (const float*)d_in[14];
  const float* fc_w    = (const float*)d_in[15];
  const float* fc_b    = (const float*)d_in[16];
  float* dout = (float*)d_out;

  char* p = (char*)d_ws;
  unsigned short* hroot_bf = (unsigned short*)p; p += (size_t)NN * 64 * 2;  // 12.8 MB
  unsigned short* xw_bf    = (unsigned short*)p; p += (size_t)NN * 64 * 2;  // 12.8 MB
  unsigned short* y_bf = (unsigned short*)p; p += (size_t)NE * 64 * 2;      // 64 MB
  unsigned short* h_bf = (unsigned short*)p; p += (size_t)NN * 64 * 2;      // 12.8 MB
  unsigned short* Wt   = (unsigned short*)p; p += (size_t)RR * 4096 * 2;
  unsigned short* wcat2 = (unsigned short*)p; p += (size_t)128 * 128 * 2;
  unsigned short* w2t  = (unsigned short*)p; p += (size_t)64 * 64 * 2;
  uint4* tse   = (uint4*)p; p += (size_t)NE * 16;       // 8 MB
  uint2* esen  = (uint2*)p; p += (size_t)NE * 8;        // 4 MB
  int* hist2   = (int*)p; p += (size_t)NN * RR * 4;     // 6.4 MB (zero region)
  float* psum_p = (float*)p; p += (size_t)NOBLK * 128 * 4;  // 3.2 MB [block][2][64]
  float* pmax_p = (float*)p; p += (size_t)NOBLK * 128 * 4;  // 3.2 MB
  int* rowptr_d = (int*)p; p += (size_t)(NDBLK * 256) * 4;  // 400 KB (NN+1 used)
  int* ctr_d   = (int*)p; p += (size_t)(NDBLK * 256) * 4;   // 400 KB (NN+1 used)
  int* bch     = (int*)p; p += (size_t)NBLK * RR * 4;   // 125 KB
  int* bbase   = (int*)p; p += (size_t)NBLK * RR * 4;   // 125 KB
  int* bsum    = (int*)p; p += (size_t)NGROUP * 4;
  int* offs    = (int*)p; p += 68;
  int* bounds  = (int*)p; p += (size_t)GG * 4;

  hipLaunchKernelGGL(k_prep, dim3(337 + ZBLK), dim3(256), 0, stream,
                     comp, bases, w1_root, w1_rel, w2, seq, Wt, wcat2, w2t, hist2, bounds);
  hipLaunchKernelGGL(k_projhists, dim3(NBLK + NPBLK), dim3(256), 0, stream,
                     x, wcat2, b1, hroot_bf, xw_bf, ei, etype, bch, hist2);
  hipLaunchKernelGGL(k_scanA, dim3(NDBLK), dim3(256), 0, stream, hist2, bsum);
  hipLaunchKernelGGL(k_bscan, dim3(1), dim3(256), 0, stream, bch, bsum, bbase, offs);
  hipLaunchKernelGGL(k_scanC, dim3(NDBLK), dim3(256), 0, stream, hist2, bsum, rowptr_d, ctr_d);
  hipLaunchKernelGGL(k_sort, dim3(NBLK), dim3(256), 0, stream,
                     ei, etype, enorm, bbase, hist2, ctr_d, tse, esen);
  hipLaunchKernelGGL(k_gconv_seg, dim3(NN / 4), dim3(256), 0, stream,
                     rowptr_d, esen, xw_bf, hroot_bf, h_bf);
  hipLaunchKernelGGL(k_rgcn_y, dim3(RR, 128), dim3(256), 0, stream,
                     tse, offs, h_bf, Wt, y_bf);
  hipLaunchKernelGGL(k_out, dim3(NOBLK), dim3(256), 0, stream,
                     rowptr_d, y_bf, h_bf, w2t, b2, bounds, psum_p, pmax_p);
  hipLaunchKernelGGL(k_head, dim3(GG), dim3(256), 0, stream, x, bounds,
                     psum_p, pmax_p, lin_w, lin_b, fc_w, fc_b, dout);
}

// Round 13
// 325.287 us; speedup vs baseline: 1.7240x; 1.0066x over previous
//
#include <hip/hip_runtime.h>
#include <hip/hip_bf16.h>

#define NN 100000   // nodes
#define NE 500000   // edges
#define FD 128      // input features
#define HD 64       // hidden
#define RR 16       // relations
#define NBASE 30    // bases
#define GG 1000     // graphs
#define CC 10       // classes
#define NGROUP 6250 // NN/16
#define NBLK ((NE + 255) / 256)   // 1954 edge-blocks
#define NDBLK ((NN + 256) / 256)  // 391 dst-scan blocks (covers NN+1 cells)
#define NOBLK (NN / 16)           // 6250 k_out blocks
#define NPBLK ((NGROUP + 3) / 4)  // 1563 proj blocks (64 rows each)
#define TOTZ (NN * RR)            // ints zeroed in k_prep tail: hist2 only
#define ZBLK ((TOTZ + 1023) / 1024)

// Per-node 64-vectors (hroot_bf, xw_bf, h_bf, y_bf) are stored sigma-order:
// stored[(c&15)*4 + (c>>4)] = true[c] (MFMA C-layout interleave). Wt/w2t have
// contraction dim sigma-permuted to match.
// wcat2 is stored in MFMA B-fragment order: [(nt*4+s)][lane l=q*16+m][8 bf16].
// Edge ordering: pos slots are per-dst (arrival order); 1/cnt(dst,r) from hist2.
// out[] pooling: k_out emits atomic-free block-partials psum_p/pmax_p
// [NOBLK][2][64] (a 16-dst block spans <=2 graphs); k_head reassembles graph g
// (slot A iff blockstart >= lo, slot B iff blockend < hi; empty slots are
// 0/-inf so over-inclusion is harmless). x is pooled directly in k_head.
// k_projhists fuses the independent hists (blocks 0..NBLK-1, dispatched first:
// they feed scanA next) and proj (blocks NBLK..) workloads into one launch.
// NOTE (R11 lesson): dst-major RGCN with LDS-atomic per-(dst,type) aggregation
// is 8x slower than this edge-major y round-trip (6.2e7 LDS bank conflicts).
// k_out phase 1 interleaves its 4 dsts (4 independent loads in flight per
// lane) — the serial dd loop was latency-bound at avg degree 5 (R12: 41us,
// nothing saturated).

typedef __attribute__((ext_vector_type(8))) short bf16x8;
typedef __attribute__((ext_vector_type(4))) float f32x4;

__device__ inline unsigned short f2b(float x) {
  __hip_bfloat16 b = __float2bfloat16(x);
  return *reinterpret_cast<unsigned short*>(&b);
}
__device__ inline float b2f(unsigned short u) {
  return __uint_as_float(((unsigned)u) << 16);
}
__device__ inline unsigned pk2(float a, float b) {
  return (unsigned)f2b(a) | ((unsigned)f2b(b) << 16);
}

__device__ inline int block_scan_incl(int v, int* ps, int t) {
  ps[t] = v;
  __syncthreads();
  for (int off = 1; off < 256; off <<= 1) {
    int u = (t >= off) ? ps[t - off] : 0;
    __syncthreads();
    ps[t] += u;
    __syncthreads();
  }
  return ps[t];
}

// ---------------- fused prep: Wt + wcat2 + w2t + bounds + zero(hist2) ----------------
__global__ void k_prep(const float* comp, const float* bases, const float* w_root,
                       const float* w_rel, const float* w2, const int* seq,
                       unsigned short* Wt, unsigned short* wcat2, unsigned short* w2t,
                       int* zbase, int* bounds) {
  int bx = blockIdx.x;
  if (bx < 256) {
    int idx = bx * 256 + threadIdx.x;  // r*4096 + k*64 + n
    int r = idx >> 12, kj = idx & 4095;
    int k = kj >> 6, n = kj & 63;
    float acc = 0.0f;
    for (int b = 0; b < NBASE; ++b)
      acc += comp[r * NBASE + b] * bases[b * 4096 + kj];
    int sk = (k & 15) * 4 + (k >> 4);
    Wt[(r << 12) + n * 64 + sk] = f2b(acc);
  } else if (bx < 336) {
    int idx = (bx - 256) * 256 + threadIdx.x;
    if (idx < 16384) {
      int n = idx >> 7, k = idx & 127;   // n: output col 0..127, k: input 0..127
      float v = (n < 64) ? w_root[k * 64 + n] : w_rel[k * 64 + (n - 64)];
      int nt = n >> 4, m = n & 15;
      int s = k >> 5, q = (k >> 3) & 3, j = k & 7;
      wcat2[(((nt * 4 + s) * 64) + q * 16 + m) * 8 + j] = f2b(v);
    } else if (idx < 16384 + 4096) {
      int i2 = idx - 16384;
      int n = i2 >> 6, k = i2 & 63;
      int sk = (k & 15) * 4 + (k >> 4);
      w2t[n * 64 + sk] = f2b(w2[k * 64 + n]);
    }
  } else if (bx == 336) {
    // bounds = inclusive cumsum of seq (1000), 250 threads x 4
    __shared__ int ps[256];
    int t = threadIdx.x;
    int loc[4];
    int ss = 0;
    if (t < 250) {
      for (int i = 0; i < 4; ++i) { loc[i] = seq[t * 4 + i]; ss += loc[i]; }
    }
    int incl = block_scan_incl(ss, ps, t);
    int base = incl - ss;
    if (t < 250) {
      int run = base;
      for (int i = 0; i < 4; ++i) { run += loc[i]; bounds[t * 4 + i] = run; }
    }
  } else {
    // zero hist2 (NN*RR ints), 1024 ints per block via int4
    int idx = (bx - 337) * 1024 + threadIdx.x * 4;
    if (idx < TOTZ)
      *reinterpret_cast<int4*>(zbase + idx) = make_int4(0, 0, 0, 0);
  }
}

// ---------------- fused: hists (blocks 0..NBLK-1) + proj MFMA (blocks NBLK..) ----------
__global__ __launch_bounds__(256) void k_projhists(
    const float* x, const unsigned short* wcat2, const float* b1,
    unsigned short* hroot_bf, unsigned short* xw_bf,
    const int* ei, const int* etype, int* bch, int* hist2) {
  __shared__ unsigned short wsh[16384];  // 32 KB, fragment-ordered (proj branch)
  __shared__ int lh[RR];                 // hists branch
  if (blockIdx.x < NBLK) {
    // ---- hists: per-block type counts + per-(dst,type) histogram ----
    if (threadIdx.x < RR) lh[threadIdx.x] = 0;
    __syncthreads();
    int e = blockIdx.x * 256 + threadIdx.x;
    if (e < NE) {
      int t = etype[e];
      atomicAdd(&lh[t], 1);
      atomicAdd(&hist2[ei[NE + e] * RR + t], 1);
    }
    __syncthreads();
    if (threadIdx.x < RR) bch[blockIdx.x * RR + threadIdx.x] = lh[threadIdx.x];
    return;
  }
  // ---- proj: hroot_bf / xw_bf (sigma), LDS-staged weights ----
  int bx = blockIdx.x - NBLK;
  int wv = threadIdx.x >> 6, l = threadIdx.x & 63, m = l & 15, q = l >> 4;
  int g = bx * 4 + wv;
  bool active = (g < NGROUP);
  int gc = active ? g : (NGROUP - 1);   // clamp so OOB waves still reach barrier
  size_t n0 = (size_t)gc * 16;
  const float* xr = x + (n0 + m) * FD + q * 8;
  float4 xv[8];
#pragma unroll
  for (int s = 0; s < 4; ++s) {
    xv[2 * s] = *reinterpret_cast<const float4*>(xr + s * 32);
    xv[2 * s + 1] = *reinterpret_cast<const float4*>(xr + s * 32 + 4);
  }
  // stage weights -> LDS (32 KB), 256 threads x 16B x 8 rounds
  {
    const uint4* wsrc = reinterpret_cast<const uint4*>(wcat2);
    uint4* wdst = reinterpret_cast<uint4*>(wsh);
#pragma unroll
    for (int r = 0; r < 8; ++r)
      wdst[r * 256 + threadIdx.x] = wsrc[r * 256 + threadIdx.x];
  }
  __syncthreads();
  if (!active) return;   // no barriers after this point
  bf16x8 afr[4];
#pragma unroll
  for (int s = 0; s < 4; ++s) {
    float4 xa = xv[2 * s], xb = xv[2 * s + 1];
    bf16x8 a;
    a[0] = (short)f2b(xa.x); a[1] = (short)f2b(xa.y);
    a[2] = (short)f2b(xa.z); a[3] = (short)f2b(xa.w);
    a[4] = (short)f2b(xb.x); a[5] = (short)f2b(xb.y);
    a[6] = (short)f2b(xb.z); a[7] = (short)f2b(xb.w);
    afr[s] = a;
  }
  f32x4 acc[8];
#pragma unroll
  for (int nt = 0; nt < 8; ++nt) acc[nt] = (f32x4){0, 0, 0, 0};
#pragma unroll
  for (int s = 0; s < 4; ++s) {
#pragma unroll
    for (int nt = 0; nt < 8; ++nt) {
      bf16x8 b = *reinterpret_cast<const bf16x8*>(wsh + (size_t)((nt * 4 + s) * 64 + l) * 8);
      acc[nt] = __builtin_amdgcn_mfma_f32_16x16x32_bf16(afr[s], b, acc[nt], 0, 0, 0);
    }
  }
  float bv[4];
#pragma unroll
  for (int nt = 0; nt < 4; ++nt) bv[nt] = b1[nt * 16 + m];
#pragma unroll
  for (int i = 0; i < 4; ++i) {
    size_t row = (n0 + q * 4 + i) * 64 + m * 4;  // sigma: stored = m*4 + nt
    uint2 oh, ox;
    oh.x = pk2(acc[0][i] + bv[0], acc[1][i] + bv[1]);
    oh.y = pk2(acc[2][i] + bv[2], acc[3][i] + bv[3]);
    ox.x = pk2(acc[4][i], acc[5][i]);
    ox.y = pk2(acc[6][i], acc[7][i]);
    *reinterpret_cast<uint2*>(hroot_bf + row) = oh;
    *reinterpret_cast<uint2*>(xw_bf + row) = ox;
  }
}

// ---------------- per-dst scan (391 blocks over NN+1 cells) ----------------
__device__ inline int dst_degree(const int* hist2, int dst) {
  const int4* hp = reinterpret_cast<const int4*>(hist2 + dst * RR);
  int4 a = hp[0], b = hp[1], c = hp[2], d = hp[3];
  return a.x + a.y + a.z + a.w + b.x + b.y + b.z + b.w +
         c.x + c.y + c.z + c.w + d.x + d.y + d.z + d.w;
}

__global__ void k_scanA(const int* hist2, int* bsum) {
  __shared__ int red[256];
  int t = threadIdx.x;
  int dst = blockIdx.x * 256 + t;
  red[t] = (dst < NN) ? dst_degree(hist2, dst) : 0;
  __syncthreads();
  for (int s = 128; s; s >>= 1) {
    if (t < s) red[t] += red[t + s];
    __syncthreads();
  }
  if (t == 0) bsum[blockIdx.x] = red[0];
}

__global__ void k_scanC(const int* hist2, const int* bsum, int* rowptr_d, int* ctr_d) {
  int t = threadIdx.x;
  int dst = blockIdx.x * 256 + t;
  int v = (dst < NN) ? dst_degree(hist2, dst) : 0;
  __shared__ int ps[256];
  int incl = block_scan_incl(v, ps, t);
  int ex = bsum[blockIdx.x] + incl - v;
  if (dst <= NN) { rowptr_d[dst] = ex; ctr_d[dst] = ex; }
}

// ---------------- bscan: bsum exclusive-scan + bbase per-block type bases + offs ----
__global__ void k_bscan(const int* bch, int* bsum, int* bbase, int* offs) {
  __shared__ int part[16][17], chunkbase[16][17];
  __shared__ int colbase[16];
  __shared__ int ps[256];
  int t = threadIdx.x;
  // --- A: exclusive scan of bsum[0..NDBLK)
  {
    int i0 = t * 2, i1 = t * 2 + 1;
    int l0 = (i0 < NDBLK) ? bsum[i0] : 0;
    int l1 = (i1 < NDBLK) ? bsum[i1] : 0;
    int sa = l0 + l1;
    int incla = block_scan_incl(sa, ps, t);
    int run = incla - sa;
    if (i0 < NDBLK) bsum[i0] = run;
    run += l0;
    if (i1 < NDBLK) bsum[i1] = run;
  }
  __syncthreads();
  // --- B: per-block type bases over bch
  int ty = t & 15, ck = t >> 4;
  const int CH = (NBLK + 15) / 16;
  int b0 = ck * CH, b1 = min(b0 + CH, NBLK);
  int s = 0;
  for (int b = b0; b < b1; ++b) s += bch[b * 16 + ty];
  part[ck][ty] = s;
  __syncthreads();
  if (t < 16) {
    int run = 0;
    for (int c = 0; c < 16; ++c) { chunkbase[c][t] = run; run += part[c][t]; }
    colbase[t] = run;  // column total
  }
  __syncthreads();
  if (t == 0) {
    int run = 0;
    for (int r = 0; r < RR; ++r) { int v = colbase[r]; offs[r] = run; colbase[r] = run; run += v; }
    offs[RR] = run;
  }
  __syncthreads();
  {
    int run = colbase[ty] + chunkbase[ck][ty];
    for (int b = b0; b < b1; ++b) {
      int v = bch[b * 16 + ty];
      bbase[b * 16 + ty] = run;
      run += v;
    }
  }
}

// ---------------- sort: per-dst pos slots; inv from hist2 ----------------
// tse[p] = {src, inv_bits, pos, 0} at type-order slot; esen[pos] = {src, norm} at dst slot.
__global__ void k_sort(const int* ei, const int* etype, const float* enorm,
                       const int* bbase, const int* hist2, int* ctr_d,
                       uint4* tse, uint2* esen) {
  __shared__ int lcnt[RR];
  if (threadIdx.x < RR) lcnt[threadIdx.x] = 0;
  __syncthreads();
  int e = blockIdx.x * 256 + threadIdx.x;
  if (e >= NE) return;
  int t = etype[e];
  int rank = atomicAdd(&lcnt[t], 1);          // LDS, block-local
  int p = bbase[blockIdx.x * RR + t] + rank;  // deterministic base (cached read)
  int src = ei[e];
  int dst = ei[NE + e];
  int cnt = hist2[dst * RR + t];              // L2-resident gather
  float inv = 1.0f / (float)max(cnt, 1);
  int pos = atomicAdd(&ctr_d[dst], 1);        // random, low-contention
  esen[pos] = make_uint2((unsigned)src, __float_as_uint(enorm[e]));
  tse[p] = make_uint4((unsigned)src, __float_as_uint(inv), (unsigned)pos, 0u);
}

// ---------------- GraphConv segment-sum: 4 edges/iter, uint2 loads (sigma space) ----------------
__global__ __launch_bounds__(256) void k_gconv_seg(const int* rowptr_d, const uint2* esen,
    const unsigned short* xw_bf, const unsigned short* hroot_bf, unsigned short* h_bf) {
  int wv = threadIdx.x >> 6, l = threadIdx.x & 63;
  int c4 = l & 15, eq = l >> 4;
  int dst = blockIdx.x * 4 + wv;
  int lo = rowptr_d[dst];
  int hi = rowptr_d[dst + 1];
  float4 acc = {0.0f, 0.0f, 0.0f, 0.0f};
  for (int base0 = lo; base0 < hi; base0 += 64) {
    int n = min(64, hi - base0);
    int sv = 0;
    float nv = 0.0f;
    if (l < n) {
      uint2 se = esen[base0 + l];
      sv = (int)se.x;
      nv = __uint_as_float(se.y);
    }
    int k4max = (n + 3) >> 2;
    for (int k4 = 0; k4 < k4max; ++k4) {
      int eid = k4 * 4 + eq;
      int s = __shfl(sv, eid);
      float w = __shfl(nv, eid);
      if (eid < n) {
        uint2 v = *reinterpret_cast<const uint2*>(xw_bf + (size_t)s * 64 + c4 * 4);
        acc.x += b2f((unsigned short)(v.x & 0xffffu)) * w;
        acc.y += b2f((unsigned short)(v.x >> 16)) * w;
        acc.z += b2f((unsigned short)(v.y & 0xffffu)) * w;
        acc.w += b2f((unsigned short)(v.y >> 16)) * w;
      }
    }
  }
  acc.x += __shfl_xor(acc.x, 16); acc.y += __shfl_xor(acc.y, 16);
  acc.z += __shfl_xor(acc.z, 16); acc.w += __shfl_xor(acc.w, 16);
  acc.x += __shfl_xor(acc.x, 32); acc.y += __shfl_xor(acc.y, 32);
  acc.z += __shfl_xor(acc.z, 32); acc.w += __shfl_xor(acc.w, 32);
  if (l < 16) {
    uint2 hb = *reinterpret_cast<const uint2*>(hroot_bf + (size_t)dst * 64 + l * 4);
    acc.x += b2f((unsigned short)(hb.x & 0xffffu));
    acc.y += b2f((unsigned short)(hb.x >> 16));
    acc.z += b2f((unsigned short)(hb.y & 0xffffu));
    acc.w += b2f((unsigned short)(hb.y >> 16));
    uint2 o;
    o.x = pk2(acc.x, acc.y);
    o.y = pk2(acc.z, acc.w);
    *reinterpret_cast<uint2*>(h_bf + (size_t)dst * 64 + l * 4) = o;
  }
}

// ---------------- RGCN via MFMA; y rows at dst-ordered slots, sigma uint2 stores ----------------
__global__ __launch_bounds__(256) void k_rgcn_y(const uint4* tse, const int* offs,
    const unsigned short* h_bf, const unsigned short* Wt, unsigned short* y_bf) {
  int r = blockIdx.x;
  int lo = offs[r], hi = offs[r + 1];
  int cnt = hi - lo;
  int wv = threadIdx.x >> 6;
  int l = threadIdx.x & 63;
  int m = l & 15, q = l >> 4;
  int ngroups = (cnt + 15) / 16;
  const unsigned short* Wr = Wt + (r << 12);
  bf16x8 bfr[2][4];
#pragma unroll
  for (int s = 0; s < 2; ++s)
#pragma unroll
    for (int nt = 0; nt < 4; ++nt)
      bfr[s][nt] = *reinterpret_cast<const bf16x8*>(Wr + (nt * 16 + m) * 64 + s * 32 + q * 8);

  for (int g = blockIdx.y * 4 + wv; g < ngroups; g += gridDim.y * 4) {
    int base = lo + g * 16;
    int ne = min(16, hi - base);
    int p = base + ((m < ne) ? m : 0);
    uint4 t4 = tse[p];
    int src = (int)t4.x;
    float inv = __uint_as_float(t4.y);
    int pos = (int)t4.z;
    f32x4 acc[4];
#pragma unroll
    for (int nt = 0; nt < 4; ++nt) acc[nt] = (f32x4){0, 0, 0, 0};
    const unsigned short* hrow = h_bf + (size_t)src * 64 + q * 8;
#pragma unroll
    for (int s = 0; s < 2; ++s) {
      bf16x8 afr = *reinterpret_cast<const bf16x8*>(hrow + s * 32);
#pragma unroll
      for (int nt = 0; nt < 4; ++nt)
        acc[nt] = __builtin_amdgcn_mfma_f32_16x16x32_bf16(afr, bfr[s][nt], acc[nt], 0, 0, 0);
    }
#pragma unroll
    for (int i = 0; i < 4; ++i) {
      int row = q * 4 + i;
      float ir = __shfl(inv, row);
      int pr = __shfl(pos, row);
      if (row < ne) {
        uint2 o;
        o.x = pk2(acc[0][i] * ir, acc[1][i] * ir);
        o.y = pk2(acc[2][i] * ir, acc[3][i] * ir);
        *reinterpret_cast<uint2*>(y_bf + (size_t)pr * 64 + m * 4) = o;
      }
    }
  }
}

// ---------------- fused: row = h@w2 + b2 + sum(y rows); block-partial pooled sum/max ----------------
// phase 1 interleaves the wave's 4 dsts: 4 independent y loads in flight/lane.
__global__ __launch_bounds__(256) void k_out(const int* rowptr_d, const unsigned short* y_bf,
    const unsigned short* h_bf, const unsigned short* w2t, const float* b2,
    const int* bounds, float* psum_p, float* pmax_p) {
  __shared__ float ldsC[16][68];   // [dst-in-block][sigma col]
  __shared__ int gidv[16];
  int wv = threadIdx.x >> 6, l = threadIdx.x & 63;
  int c4 = l & 15, eq = l >> 4;
  size_t d0 = (size_t)blockIdx.x * 16;
  // graph ids for the 16 dsts (binary search over bounds), overlapped with phase 1
  if (threadIdx.x < 16) {
    int dst = (int)d0 + threadIdx.x;
    int lo2 = 0, hi2 = GG;
    while (lo2 < hi2) {
      int mid = (lo2 + hi2) >> 1;
      if (bounds[mid] <= dst) lo2 = mid + 1; else hi2 = mid;
    }
    gidv[threadIdx.x] = lo2;
  }
  int lo4[4], deg4[4];
#pragma unroll
  for (int dd = 0; dd < 4; ++dd) {
    int dst = (int)d0 + wv * 4 + dd;
    lo4[dd] = rowptr_d[dst];
    deg4[dd] = rowptr_d[dst + 1] - lo4[dd];
  }
  int maxd = max(max(deg4[0], deg4[1]), max(deg4[2], deg4[3]));
  float4 acc4[4];
#pragma unroll
  for (int dd = 0; dd < 4; ++dd) acc4[dd] = make_float4(0.0f, 0.0f, 0.0f, 0.0f);
  for (int base = eq; base < maxd; base += 4) {
#pragma unroll
    for (int dd = 0; dd < 4; ++dd) {
      if (base < deg4[dd]) {
        uint2 v = *reinterpret_cast<const uint2*>(
            y_bf + (size_t)(lo4[dd] + base) * 64 + c4 * 4);
        acc4[dd].x += b2f((unsigned short)(v.x & 0xffffu));
        acc4[dd].y += b2f((unsigned short)(v.x >> 16));
        acc4[dd].z += b2f((unsigned short)(v.y & 0xffffu));
        acc4[dd].w += b2f((unsigned short)(v.y >> 16));
      }
    }
  }
#pragma unroll
  for (int dd = 0; dd < 4; ++dd) {
    float4 acc = acc4[dd];
    acc.x += __shfl_xor(acc.x, 16); acc.y += __shfl_xor(acc.y, 16);
    acc.z += __shfl_xor(acc.z, 16); acc.w += __shfl_xor(acc.w, 16);
    acc.x += __shfl_xor(acc.x, 32); acc.y += __shfl_xor(acc.y, 32);
    acc.z += __shfl_xor(acc.z, 32); acc.w += __shfl_xor(acc.w, 32);
    if (l < 16)
      *reinterpret_cast<float4*>(&ldsC[wv * 4 + dd][l * 4]) = acc;
  }
  __syncthreads();
  // phase 2: wave wv owns true cols wv*16 + m; y-sum for that col is at sigma m*4+wv
  int m = l & 15, q = l >> 4, nt = wv;
  float bb = b2[nt * 16 + m];
  f32x4 acc;
#pragma unroll
  for (int i = 0; i < 4; ++i) acc[i] = ldsC[q * 4 + i][m * 4 + nt] + bb;
#pragma unroll
  for (int s = 0; s < 2; ++s) {
    bf16x8 a = *reinterpret_cast<const bf16x8*>(h_bf + (d0 + m) * 64 + s * 32 + q * 8);
    bf16x8 b = *reinterpret_cast<const bf16x8*>(w2t + (nt * 16 + m) * 64 + s * 32 + q * 8);
    acc = __builtin_amdgcn_mfma_f32_16x16x32_bf16(a, b, acc, 0, 0, 0);
  }
  // pooled epilogue: slot A = graph of dst d0, slot B = graph of dst d0+15
  int c = nt * 16 + m;
  int gA = gidv[0];
  float sA = 0.0f, xA = -3.4e38f, sB = 0.0f, xB = -3.4e38f;
#pragma unroll
  for (int i = 0; i < 4; ++i) {
    int gi = gidv[q * 4 + i];
    if (gi == gA) { sA += acc[i]; xA = fmaxf(xA, acc[i]); }
    else          { sB += acc[i]; xB = fmaxf(xB, acc[i]); }
  }
#pragma unroll
  for (int off = 16; off <= 32; off <<= 1) {
    sA += __shfl_xor(sA, off); xA = fmaxf(xA, __shfl_xor(xA, off));
    sB += __shfl_xor(sB, off); xB = fmaxf(xB, __shfl_xor(xB, off));
  }
  if (q == 0) {
    size_t base = (size_t)blockIdx.x * 128;
    psum_p[base + c] = sA;
    psum_p[base + 64 + c] = sB;
    pmax_p[base + c] = xA;
    pmax_p[base + 64 + c] = xB;
  }
}

// ---------------- fused pool(x) + block-partial(out) + MLP head + log_softmax ----------------
__global__ __launch_bounds__(256) void k_head(const float* x, const int* bounds,
    const float* psum_p, const float* pmax_p, const float* lin_w, const float* lin_b,
    const float* fc_w, const float* fc_b, float* dout) {
  __shared__ float4 psum[8][32], pmax[8][32];
  __shared__ float gsum[192], gmax[192];
  __shared__ float part[4][64];
  __shared__ float hid[HD], lg[CC], mred[2];
  int g = blockIdx.x, t = threadIdx.x;
  int lo = (g == 0) ? 0 : bounds[g - 1];
  int hi = bounds[g];
  int nn = hi - lo;
  {
    int c4 = t & 31, ch = t >> 5;   // 8 chunks x 32 col-groups over x's 128 cols
    int a = lo + (nn * ch) / 8, b = lo + (nn * (ch + 1)) / 8;
    float4 s = {0, 0, 0, 0};
    float4 mx = {-3.4e38f, -3.4e38f, -3.4e38f, -3.4e38f};
    const float* bp = x + (size_t)a * FD + c4 * 4;
    int n = a;
    for (; n + 4 <= b; n += 4) {
      float4 v0 = *reinterpret_cast<const float4*>(bp);
      float4 v1 = *reinterpret_cast<const float4*>(bp + FD);
      float4 v2 = *reinterpret_cast<const float4*>(bp + 2 * FD);
      float4 v3 = *reinterpret_cast<const float4*>(bp + 3 * FD);
      bp += 4 * FD;
      s.x += v0.x + v1.x + v2.x + v3.x;
      s.y += v0.y + v1.y + v2.y + v3.y;
      s.z += v0.z + v1.z + v2.z + v3.z;
      s.w += v0.w + v1.w + v2.w + v3.w;
      mx.x = fmaxf(fmaxf(fmaxf(mx.x, v0.x), fmaxf(v1.x, v2.x)), v3.x);
      mx.y = fmaxf(fmaxf(fmaxf(mx.y, v0.y), fmaxf(v1.y, v2.y)), v3.y);
      mx.z = fmaxf(fmaxf(fmaxf(mx.z, v0.z), fmaxf(v1.z, v2.z)), v3.z);
      mx.w = fmaxf(fmaxf(fmaxf(mx.w, v0.w), fmaxf(v1.w, v2.w)), v3.w);
    }
    for (; n < b; ++n) {
      float4 v = *reinterpret_cast<const float4*>(bp);
      bp += FD;
      s.x += v.x; s.y += v.y; s.z += v.z; s.w += v.w;
      mx.x = fmaxf(mx.x, v.x); mx.y = fmaxf(mx.y, v.y);
      mx.z = fmaxf(mx.z, v.z); mx.w = fmaxf(mx.w, v.w);
    }
    psum[ch][c4] = s;
    pmax[ch][c4] = mx;
  }
  __syncthreads();
  if (t < 32) {
    float4 s = psum[0][t], m = pmax[0][t];
#pragma unroll
    for (int ch = 1; ch < 8; ++ch) {
      float4 ps = psum[ch][t], pm = pmax[ch][t];
      s.x += ps.x; s.y += ps.y; s.z += ps.z; s.w += ps.w;
      m.x = fmaxf(m.x, pm.x); m.y = fmaxf(m.y, pm.y);
      m.z = fmaxf(m.z, pm.z); m.w = fmaxf(m.w, pm.w);
    }
    gsum[t * 4 + 0] = s.x; gsum[t * 4 + 1] = s.y;
    gsum[t * 4 + 2] = s.z; gsum[t * 4 + 3] = s.w;
    gmax[t * 4 + 0] = m.x; gmax[t * 4 + 1] = m.y;
    gmax[t * 4 + 2] = m.z; gmax[t * 4 + 3] = m.w;
  } else if (t < 96) {
    // out pools: 16-row blocks
    int c = t - 32;
    int blo = lo >> 4, bhi = (hi - 1) >> 4;
    float s = 0.0f, mx = -3.4e38f;
    for (int b = blo; b <= bhi; ++b) {
      size_t base = (size_t)b * 128;
      if (b * 16 >= lo) {          // slot A belongs to g
        s += psum_p[base + c];
        mx = fmaxf(mx, pmax_p[base + c]);
      }
      if (b * 16 + 15 < hi) {      // slot B belongs to g (or empty: +0 / -inf)
        s += psum_p[base + 64 + c];
        mx = fmaxf(mx, pmax_p[base + 64 + c]);
      }
    }
    gsum[128 + c] = s;
    gmax[128 + c] = mx;
  }
  __syncthreads();
  {
    int o = t & 63, pp = t >> 6;
    float a = 0.0f;
    int k0 = pp * 96;
    for (int k = k0; k < k0 + 96; ++k) {
      float gv = (k < 192) ? gsum[k] : gmax[k - 192];
      a += gv * lin_w[k * 64 + o];
    }
    part[pp][o] = a;
  }
  __syncthreads();
  if (t < HD) {
    float a = lin_b[t] + part[0][t] + part[1][t] + part[2][t] + part[3][t];
    hid[t] = fmaxf(a, 0.0f);
  }
  __syncthreads();
  if (t < CC) {
    float a = fc_b[t];
    for (int k = 0; k < HD; ++k) a += hid[k] * fc_w[k * CC + t];
    lg[t] = a;
  }
  __syncthreads();
  if (t == 0) {
    float mm = lg[0];
#pragma unroll
    for (int i = 1; i < CC; ++i) mm = fmaxf(mm, lg[i]);
    float se = 0.0f;
#pragma unroll
    for (int i = 0; i < CC; ++i) se += __expf(lg[i] - mm);
    mred[0] = mm;
    mred[1] = __logf(se);
  }
  __syncthreads();
  if (t < CC) dout[g * CC + t] = lg[t] - mred[0] - mred[1];
}

extern "C" void kernel_launch(void* const* d_in, const int* in_sizes, int n_in,
                              void* d_out, int out_size, void* d_ws, size_t ws_size,
                              hipStream_t stream) {
  const float* x     = (const float*)d_in[0];
  const int* ei      = (const int*)d_in[1];
  const float* enorm = (const float*)d_in[2];
  const int* etype   = (const int*)d_in[3];
  const int* seq     = (const int*)d_in[4];
  const float* w1_rel  = (const float*)d_in[6];
  const float* w1_root = (const float*)d_in[7];
  const float* b1      = (const float*)d_in[8];
  const float* bases   = (const float*)d_in[9];
  const float* comp    = (const float*)d_in[10];
  const float* w2      = (const float*)d_in[11];
  const float* b2      = (const float*)d_in[12];
  const float* lin_w   = (const float*)d_in[13];
  const float* lin_b   = (const float*)d_in[14];
  const float* fc_w    = (const float*)d_in[15];
  const float* fc_b    = (const float*)d_in[16];
  float* dout = (float*)d_out;

  char* p = (char*)d_ws;
  unsigned short* hroot_bf = (unsigned short*)p; p += (size_t)NN * 64 * 2;  // 12.8 MB
  unsigned short* xw_bf    = (unsigned short*)p; p += (size_t)NN * 64 * 2;  // 12.8 MB
  unsigned short* y_bf = (unsigned short*)p; p += (size_t)NE * 64 * 2;      // 64 MB
  unsigned short* h_bf = (unsigned short*)p; p += (size_t)NN * 64 * 2;      // 12.8 MB
  unsigned short* Wt   = (unsigned short*)p; p += (size_t)RR * 4096 * 2;
  unsigned short* wcat2 = (unsigned short*)p; p += (size_t)128 * 128 * 2;
  unsigned short* w2t  = (unsigned short*)p; p += (size_t)64 * 64 * 2;
  uint4* tse   = (uint4*)p; p += (size_t)NE * 16;       // 8 MB
  uint2* esen  = (uint2*)p; p += (size_t)NE * 8;        // 4 MB
  int* hist2   = (int*)p; p += (size_t)NN * RR * 4;     // 6.4 MB (zero region)
  float* psum_p = (float*)p; p += (size_t)NOBLK * 128 * 4;  // 3.2 MB [block][2][64]
  float* pmax_p = (float*)p; p += (size_t)NOBLK * 128 * 4;  // 3.2 MB
  int* rowptr_d = (int*)p; p += (size_t)(NDBLK * 256) * 4;  // 400 KB (NN+1 used)
  int* ctr_d   = (int*)p; p += (size_t)(NDBLK * 256) * 4;   // 400 KB (NN+1 used)
  int* bch     = (int*)p; p += (size_t)NBLK * RR * 4;   // 125 KB
  int* bbase   = (int*)p; p += (size_t)NBLK * RR * 4;   // 125 KB
  int* bsum    = (int*)p; p += (size_t)NGROUP * 4;
  int* offs    = (int*)p; p += 68;
  int* bounds  = (int*)p; p += (size_t)GG * 4;

  hipLaunchKernelGGL(k_prep, dim3(337 + ZBLK), dim3(256), 0, stream,
                     comp, bases, w1_root, w1_rel, w2, seq, Wt, wcat2, w2t, hist2, bounds);
  hipLaunchKernelGGL(k_projhists, dim3(NBLK + NPBLK), dim3(256), 0, stream,
                     x, wcat2, b1, hroot_bf, xw_bf, ei, etype, bch, hist2);
  hipLaunchKernelGGL(k_scanA, dim3(NDBLK), dim3(256), 0, stream, hist2, bsum);
  hipLaunchKernelGGL(k_bscan, dim3(1), dim3(256), 0, stream, bch, bsum, bbase, offs);
  hipLaunchKernelGGL(k_scanC, dim3(NDBLK), dim3(256), 0, stream, hist2, bsum, rowptr_d, ctr_d);
  hipLaunchKernelGGL(k_sort, dim3(NBLK), dim3(256), 0, stream,
                     ei, etype, enorm, bbase, hist2, ctr_d, tse, esen);
  hipLaunchKernelGGL(k_gconv_seg, dim3(NN / 4), dim3(256), 0, stream,
                     rowptr_d, esen, xw_bf, hroot_bf, h_bf);
  hipLaunchKernelGGL(k_rgcn_y, dim3(RR, 128), dim3(256), 0, stream,
                     tse, offs, h_bf, Wt, y_bf);
  hipLaunchKernelGGL(k_out, dim3(NOBLK), dim3(256), 0, stream,
                     rowptr_d, y_bf, h_bf, w2t, b2, bounds, psum_p, pmax_p);
  hipLaunchKernelGGL(k_head, dim3(GG), dim3(256), 0, stream, x, bounds,
                     psum_p, pmax_p, lin_w, lin_b, fc_w, fc_b, dout);
}